// Round 7
// baseline (457.542 us; speedup 1.0000x reference)
//
#include <hip/hip_runtime.h>

// CrossAttention: LN -> proj GEMMs -> logits GEMM -> fused softmax+T -> 2 PV GEMMs.
// GEMM v7: 128x128 tile, 256 threads (2x2 waves, 64x64/wave), BK=32, 2-buf
// LDS = 32 KiB -> ~3 blocks/CU (VGPR ~130): cross-block TLP covers the
// vmcnt(0)/barrier drain (m97/m114 mechanism) instead of 1-block phase magic.
// Stage t+1 issued FIRST each iteration (max distance to the end-of-iter wait).
// LDS window layout per [buf][mat]: [8 windows][512 shorts]; window = 16 rows
// x 4 chunks; chunk (fr,q) at L=(fr>>1)*8+((q+4*(fr&1))^((fr>>1)&7)) --
// measured 0 bank conflicts (R4/R6).
// Workspace layout (196 MiB):
//   R1 [0,      64MiB): norm_img|norm_txt  -> reused as projT_img|projT_txt
//   R2 [64MiB, 128MiB): attnT (written by fused softmax)
//   WB [128MiB,132MiB): W_img|W_txt as bf16
//   R4 [132MiB,196MiB): logits bf16 -> softmax in place -> attn

#define DEV __device__ __forceinline__

typedef short s16x8 __attribute__((ext_vector_type(8)));
typedef float f32x4 __attribute__((ext_vector_type(4)));

DEV unsigned short f2bf(float f){            // fp32 -> bf16, round-nearest-even
  unsigned u = __float_as_uint(f);
  u = (u + 0x7fffu + ((u >> 16) & 1u)) >> 16;
  return (unsigned short)u;
}
DEV float bf2f(unsigned short s){ return __uint_as_float(((unsigned)s) << 16); }

DEV void ldsload16(const void* g, void* l){
  __builtin_amdgcn_global_load_lds((const __attribute__((address_space(1))) void*)g,
                                   (__attribute__((address_space(3))) void*)l, 16, 0, 0);
}

// ---------------- fp32 -> bf16 convert ----------------
__global__ __launch_bounds__(256) void k_cvt(const float* __restrict__ src,
                                             unsigned short* __restrict__ dst, int n4){
  int i = blockIdx.x * 256 + threadIdx.x;
  if (i < n4){
    float4 v = ((const float4*)src)[i];
    ushort4 o;
    o.x = f2bf(v.x); o.y = f2bf(v.y); o.z = f2bf(v.z); o.w = f2bf(v.w);
    ((ushort4*)dst)[i] = o;
  }
}

// ---------------- LayerNorm (D=1024) fp32 -> bf16 ----------------
__global__ __launch_bounds__(256) void k_ln(const float* __restrict__ x,
                                            const float* __restrict__ w,
                                            const float* __restrict__ b,
                                            unsigned short* __restrict__ y){
  int row = blockIdx.x, tid = threadIdx.x;
  float4 v = ((const float4*)(x + (size_t)row * 1024))[tid];
  float s  = v.x + v.y + v.z + v.w;
  float s2 = v.x*v.x + v.y*v.y + v.z*v.z + v.w*v.w;
  #pragma unroll
  for (int o = 32; o > 0; o >>= 1){ s += __shfl_xor(s, o, 64); s2 += __shfl_xor(s2, o, 64); }
  __shared__ float sh[8];
  int wv = tid >> 6, ln = tid & 63;
  if (!ln){ sh[wv] = s; sh[4 + wv] = s2; }
  __syncthreads();
  s  = sh[0] + sh[1] + sh[2] + sh[3];
  s2 = sh[4] + sh[5] + sh[6] + sh[7];
  float mean = s * (1.f/1024.f);
  float var  = s2 * (1.f/1024.f) - mean * mean;
  float rstd = rsqrtf(var + 1e-5f);
  float4 w4 = ((const float4*)w)[tid];
  float4 b4 = ((const float4*)b)[tid];
  ushort4 o;
  o.x = f2bf((v.x-mean)*rstd*w4.x + b4.x);
  o.y = f2bf((v.y-mean)*rstd*w4.y + b4.y);
  o.z = f2bf((v.z-mean)*rstd*w4.z + b4.z);
  o.w = f2bf((v.w-mean)*rstd*w4.w + b4.w);
  ((ushort4*)(y + (size_t)row * 1024))[tid] = o;
}

// ---------------- bf16 B^T GEMM, 128x128, BK=32, 2-buf, 3 blocks/CU --------
// C[m,n] = scale * sum_k A[m,k]*Bt[n,k] + bias[n].  Requires NT = K/32 >= 2.
// STG: stage one matrix k-slice of tile T: wave w fills windows w and w+4.
#define STG(MAT, BASE, LD, T) do{                                                 \
  ldsload16((BASE) + (size_t)(wave*16 + sfr) * (LD) + (T)*32 + sq*8,              \
            &MAT[(T)&1][wave][0]);                                                \
  ldsload16((BASE) + (size_t)(wave*16 + 64 + sfr) * (LD) + (T)*32 + sq*8,         \
            &MAT[(T)&1][wave + 4][0]);                                            \
}while(0)

template<int OUT_BF16>
__global__ __launch_bounds__(256, 3) void k_gemm128(const unsigned short* __restrict__ A,
                                                    const unsigned short* __restrict__ Bt,
                                                    void* __restrict__ C,
                                                    const float* __restrict__ bias, float scale,
                                                    int K, int lda, int ldb, int ldc,
                                                    long sA, long sB, long sC,
                                                    int NBX, int NBY){
  __shared__ __align__(16) unsigned short As[2][8][512];   // [buf][window][1KiB]
  __shared__ __align__(16) unsigned short Bs[2][8][512];
  int nwg = gridDim.x;                       // always a multiple of 8 here
  int bid = blockIdx.x;
  int swz = (bid & 7) * (nwg >> 3) + (bid >> 3);   // bijective XCD swizzle (T1)
  int bx = swz % NBX; int rem = swz / NBX;
  int by = rem % NBY; int bz = rem / NBY;

  int tid = threadIdx.x, lane = tid & 63, wave = tid >> 6;
  int wm = wave >> 1, wn = wave & 1;         // 2 x 2 wave grid
  int q = lane >> 4, fr = lane & 15;
  const unsigned short* Ab = A  + (size_t)bz * sA + (size_t)by * 128 * lda;
  const unsigned short* Bb = Bt + (size_t)bz * sB + (size_t)bx * 128 * ldb;
  // staging statics: lane writes window chunk `lane`; inverse of placement map
  int v   = (lane & 7) ^ ((lane >> 3) & 7);
  int sfr = 2 * (lane >> 3) + (v >> 2);      // source row within window (0..15)
  int sq  = v & 3;                           // source k-chunk (0..3)
  // read statics: placement of (fr, q) within a window, in shorts
  int roff = ((fr >> 1) << 6) + (((q + ((fr & 1) << 2)) ^ ((fr >> 1) & 7)) << 3);
  const int NT = K >> 5;

  f32x4 acc[4][4];
  #pragma unroll
  for (int m = 0; m < 4; ++m)
    #pragma unroll
    for (int n = 0; n < 4; ++n) acc[m][n] = f32x4{0.f, 0.f, 0.f, 0.f};

  // prologue: stage tile 0 -> buf 0
  STG(As, Ab, lda, 0); STG(Bs, Bb, ldb, 0);
  asm volatile("s_waitcnt vmcnt(0)");
  __builtin_amdgcn_s_barrier();

  for (int t = 0; t < NT; ++t){
    const int buf = t & 1;
    if (t + 1 < NT){ STG(As, Ab, lda, t + 1); STG(Bs, Bb, ldb, t + 1); }
    s16x8 af[4], bfr[4];
    #pragma unroll
    for (int mi = 0; mi < 4; ++mi) af[mi] = *(const s16x8*)&As[buf][wm*4 + mi][roff];
    #pragma unroll
    for (int n = 0; n < 4; ++n)   bfr[n]  = *(const s16x8*)&Bs[buf][wn*4 + n][roff];
    asm volatile("s_waitcnt lgkmcnt(0)");
    __builtin_amdgcn_sched_barrier(0);       // rule 18: MFMA must not hoist above
    __builtin_amdgcn_s_setprio(1);
    #pragma unroll
    for (int mi = 0; mi < 4; ++mi)
      #pragma unroll
      for (int n = 0; n < 4; ++n)
        acc[mi][n] = __builtin_amdgcn_mfma_f32_16x16x32_bf16(af[mi], bfr[n], acc[mi][n], 0, 0, 0);
    __builtin_amdgcn_s_setprio(0);
    __builtin_amdgcn_sched_barrier(0);       // keep the drain after the MFMAs
    asm volatile("s_waitcnt vmcnt(0)");      // t+1 landed; other blocks cover this
    __builtin_amdgcn_s_barrier();
  }
  // epilogue
  size_t cb = (size_t)bz * sC;
  int row0 = by*128 + wm*64 + q*4;
  int col0 = bx*128 + wn*64 + fr;
  #pragma unroll
  for (int m = 0; m < 4; ++m){
    #pragma unroll
    for (int n = 0; n < 4; ++n){
      int col = col0 + n*16;
      float bv = bias ? bias[col] : 0.f;
      #pragma unroll
      for (int j = 0; j < 4; ++j){
        int row = row0 + m*16 + j;
        float vv = acc[m][n][j] * scale + bv;
        if (OUT_BF16) ((unsigned short*)C)[cb + (size_t)row*ldc + col] = f2bf(vv);
        else          ((float*)C)[cb + (size_t)row*ldc + col] = vv;
      }
    }
  }
}

// ---------------- bf16 transpose, 64x64 tiles, swizzled LDS ----------------
__global__ __launch_bounds__(256) void k_transpose(const unsigned short* __restrict__ src,
                                                   unsigned short* __restrict__ dst,
                                                   int R, int C, long sS, long sD){
  __shared__ __align__(16) unsigned short tile[64 * 64];
  int tid = threadIdx.x;
  const unsigned short* sb = src + (size_t)blockIdx.z * sS;
  unsigned short* db = dst + (size_t)blockIdx.z * sD;
  int r0 = blockIdx.y * 64, c0 = blockIdx.x * 64;
  #pragma unroll
  for (int i = 0; i < 2; ++i){
    int ci = i * 256 + tid;
    int row = ci >> 3, cch = ci & 7;
    int pos = cch ^ (row & 7) ^ (row >> 3);
    uint4 v = *(const uint4*)&sb[(size_t)(r0 + row) * C + c0 + cch * 8];
    *(uint4*)&tile[row * 64 + pos * 8] = v;
  }
  __syncthreads();
  int ocp = tid >> 3, og = tid & 7;
  int oc = ocp * 2;
  union { uint4 v; unsigned short us[8]; } o0, o1;
  #pragma unroll
  for (int k = 0; k < 8; ++k){
    int r = og * 8 + k;
    int pos = (oc >> 3) ^ (r & 7) ^ (r >> 3);
    unsigned pr = *(const unsigned*)&tile[r * 64 + pos * 8 + (oc & 7)];
    o0.us[k] = (unsigned short)(pr & 0xffffu);
    o1.us[k] = (unsigned short)(pr >> 16);
  }
  *(uint4*)&db[(size_t)(c0 + oc    ) * R + r0 + og * 8] = o0.v;
  *(uint4*)&db[(size_t)(c0 + oc + 1) * R + r0 + og * 8] = o1.v;
}

// -------- fused row softmax (2048) + transposed copy, bf16 ----------------
// Block: 64 rows (stripe). 3 streaming passes (max, sum, normalize);
// pass 3 writes row-major in place AND attnT via 64x64 LDS transpose tiles.
__global__ __launch_bounds__(256) void k_softmax_t(unsigned short* __restrict__ a,
                                                   unsigned short* __restrict__ at){
  __shared__ __align__(16) unsigned short tile[64 * 64];
  int tid = threadIdx.x;
  int r = tid >> 2, sub = tid & 3;
  size_t boff = (size_t)blockIdx.y * 4194304;
  int r0 = blockIdx.x * 64;
  unsigned short* prow = a + boff + (size_t)(r0 + r) * 2048;
  // pass 1: row max (4 threads per row, interleaved 8-elem chunks)
  float mx = -3.0e38f;
  for (int i = 0; i < 64; ++i){
    union { uint4 v; unsigned short us[8]; } u;
    u.v = *(const uint4*)&prow[(sub + 4*i) * 8];
    #pragma unroll
    for (int j = 0; j < 8; ++j) mx = fmaxf(mx, bf2f(u.us[j]));
  }
  mx = fmaxf(mx, __shfl_xor(mx, 1, 64));
  mx = fmaxf(mx, __shfl_xor(mx, 2, 64));
  // pass 2: row sum of exp
  float s = 0.f;
  for (int i = 0; i < 64; ++i){
    union { uint4 v; unsigned short us[8]; } u;
    u.v = *(const uint4*)&prow[(sub + 4*i) * 8];
    #pragma unroll
    for (int j = 0; j < 8; ++j) s += __expf(bf2f(u.us[j]) - mx);
  }
  s += __shfl_xor(s, 1, 64);
  s += __shfl_xor(s, 2, 64);
  float inv = 1.f / s;
  // pass 3: normalize; write row-major in place + transposed via LDS
  int ocp = tid >> 3, og = tid & 7, oc = ocp * 2;
  for (int cb = 0; cb < 32; ++cb){
    #pragma unroll
    for (int jj = 0; jj < 2; ++jj){
      int j = sub + jj*4;                    // chunk within this 64-col block
      int c8 = cb*8 + j;                     // global 8-elem chunk
      union { uint4 v; unsigned short us[8]; } u, o;
      u.v = *(const uint4*)&prow[c8 * 8];
      #pragma unroll
      for (int k = 0; k < 8; ++k) o.us[k] = f2bf(__expf(bf2f(u.us[k]) - mx) * inv);
      *(uint4*)&prow[c8 * 8] = o.v;
      int pos = j ^ (r & 7) ^ (r >> 3);
      *(uint4*)&tile[r * 64 + pos * 8] = o.v;
    }
    __syncthreads();
    union { uint4 v; unsigned short us[8]; } o0, o1;
    #pragma unroll
    for (int k = 0; k < 8; ++k){
      int rr = og * 8 + k;
      int pos = (oc >> 3) ^ (rr & 7) ^ (rr >> 3);
      unsigned pr = *(const unsigned*)&tile[rr * 64 + pos * 8 + (oc & 7)];
      o0.us[k] = (unsigned short)(pr & 0xffffu);
      o1.us[k] = (unsigned short)(pr >> 16);
    }
    size_t c0 = (size_t)cb * 64;
    *(uint4*)&at[boff + (c0 + oc    ) * 2048 + r0 + og * 8] = o0.v;
    *(uint4*)&at[boff + (c0 + oc + 1) * 2048 + r0 + og * 8] = o1.v;
    __syncthreads();
  }
}

extern "C" void kernel_launch(void* const* d_in, const int* in_sizes, int n_in,
                              void* d_out, int out_size, void* d_ws, size_t ws_size,
                              hipStream_t stream) {
  const float* img  = (const float*)d_in[0];   // [8,2048,1024]
  const float* txt  = (const float*)d_in[1];   // [8,2048,1024]
  const float* lnw  = (const float*)d_in[2];   // [1024]
  const float* lnb  = (const float*)d_in[3];   // [1024]
  const float* Wimg = (const float*)d_in[4];   // [1024,1024]
  const float* bimg = (const float*)d_in[5];   // [1024]
  const float* Wtxt = (const float*)d_in[6];   // [1024,1024]
  const float* btxt = (const float*)d_in[7];   // [1024]
  float* out = (float*)d_out;                  // image_out | text_out

  char* ws = (char*)d_ws;
  unsigned short* R1 = (unsigned short*)ws;                   // 33.5M elems
  unsigned short* R2 = (unsigned short*)(ws + 67108864);      // 33.5M elems
  unsigned short* WB = (unsigned short*)(ws + 134217728);     // 2x1M elems
  unsigned short* R4 = (unsigned short*)(ws + 138412032);     // 33.5M elems

  const long PB = 2097152;   // proj per-batch elems (2048*1024)
  const long AB = 4194304;   // attn per-batch elems (2048*2048)

  // W -> bf16
  k_cvt<<<1024, 256, 0, stream>>>(Wimg, WB,           262144);
  k_cvt<<<1024, 256, 0, stream>>>(Wtxt, WB + 1048576, 262144);
  // LayerNorm -> bf16 norms in R1
  k_ln<<<16384, 256, 0, stream>>>(img, lnw, lnb, R1);
  k_ln<<<16384, 256, 0, stream>>>(txt, lnw, lnb, R1 + 16777216);
  // Projections: [16384,1024] = norm @ W^T + b  -> bf16 proj in R2
  k_gemm128<1><<<1024, 256, 0, stream>>>(R1,            WB,           R2,            bimg, 1.f,
                                         1024, 1024, 1024, 1024, 0, 0, 0, 8, 128);
  k_gemm128<1><<<1024, 256, 0, stream>>>(R1 + 16777216, WB + 1048576, R2 + 16777216, btxt, 1.f,
                                         1024, 1024, 1024, 1024, 0, 0, 0, 8, 128);
  // projT (per batch [1024][2048]) into R1 (norms dead)
  dim3 gt(16, 32, 8);
  k_transpose<<<gt, 256, 0, stream>>>(R2,            R1,            2048, 1024, PB, PB);
  k_transpose<<<gt, 256, 0, stream>>>(R2 + 16777216, R1 + 16777216, 2048, 1024, PB, PB);
  // logits[b] = proj_img[b] @ proj_txt[b]^T / 32  -> bf16 in R4
  k_gemm128<1><<<2048, 256, 0, stream>>>(R2, R2 + 16777216, R4, nullptr, 0.03125f,
                                         1024, 1024, 1024, 2048, PB, PB, AB, 16, 16);
  // fused softmax + attnT (R4 normalized in place; R2 <- attnT; proj dead)
  dim3 gs(32, 8);
  k_softmax_t<<<gs, 256, 0, stream>>>(R4, R2);
  // image_out[b] = attn[b] @ txtpT[b]^T   (fp32 -> d_out)
  k_gemm128<0><<<1024, 256, 0, stream>>>(R4, R1 + 16777216, out, nullptr, 1.f,
                                         2048, 2048, 2048, 1024, AB, PB, PB, 8, 16);
  // text_out[b] = attnT[b] @ imgpT[b]^T
  k_gemm128<0><<<1024, 256, 0, stream>>>(R2, R1, out + 16777216, nullptr, 1.f,
                                         2048, 2048, 2048, 1024, AB, PB, PB, 8, 16);
}